// Round 3
// baseline (913.203 us; speedup 1.0000x reference)
//
#include <hip/hip_runtime.h>

#define NB 512
#define NC 32
#define NT 8192
#define TP 1024            // NT/8 pooled windows
#define NG 11

typedef float f32x4 __attribute__((ext_vector_type(4)));

// One wave covers 32 windows (256 samples = 1 KB per channel row).
// Every vmem instruction is fully dense: lane i loads float4 at +16B*i.
// Lane 2k holds the first-half sum of window k, lane 2k+1 the second half;
// the epilogue recombines with shuffles. No LDS, acc[11] regs per thread.
__global__ __launch_bounds__(256, 6) void local_gnn_kernel(
    const float* __restrict__ xg,
    const float* __restrict__ W,
    const float* __restrict__ bias,
    float* __restrict__ out)
{
    const int lane = threadIdx.x & 63;
    const int y    = threadIdx.x >> 6;       // wave in block (0..3) — uniform
    const int bb   = blockIdx.x >> 3;        // batch
    const int t8   = blockIdx.x & 7;         // 128-window tile within batch
    const int wt0  = t8 * 128 + y * 32;      // first window of this wave
    const int off  = wt0 * 8 + 4 * lane;     // first sample this lane loads

    constexpr int NCH = 29;                  // channels 7, 18, 25 unused
    constexpr int CH[NCH]  = {0,1,2,3,4,5,6,8,9,10,11,12,13,14,15,
                              16,17,19,20,21,22,23,24,26,27,28,29,30,31};
    constexpr int GRP[NCH] = {0,0,1,1,2,2,6,7,7,8,8,9,10,10,8,
                              3,3,4,4,5,5,6,6,8,7,8,8,9,10};

    float acc[NG];
    #pragma unroll
    for (int g = 0; g < NG; ++g) acc[g] = 0.0f;

    const float* xb = xg + (size_t)bb * (NC * NT) + off;
    const float* Wb = W + off;

    #pragma unroll
    for (int i = 0; i < NCH; ++i) {
        const int c = CH[i];
        f32x4 xv = __builtin_nontemporal_load((const f32x4*)(xb + c * NT));
        f32x4 wv = *(const f32x4*)(Wb + c * NT);
        const float bc = bias[c];
        float s;
        s  = fmaxf(fmaf(xv.x, wv.x, -bc), 0.0f);
        s += fmaxf(fmaf(xv.y, wv.y, -bc), 0.0f);
        s += fmaxf(fmaf(xv.z, wv.z, -bc), 0.0f);
        s += fmaxf(fmaf(xv.w, wv.w, -bc), 0.0f);
        acc[GRP[i]] += s;   // half-window partial
    }

    // divisor = 8 (pool) * group size {2,2,2,2,2,2,3,3,6,2,3}
    constexpr float INV[NG] = {1.f/16, 1.f/16, 1.f/16, 1.f/16, 1.f/16, 1.f/16,
                               1.f/24, 1.f/24, 1.f/48, 1.f/16, 1.f/24};

    // Recombine half-window sums: window j (0..31) = lane 2j + lane 2j+1.
    // Lanes 0..31 store 128 B dense per group.
    const int j = lane & 31;
    float* ob = out + (size_t)bb * (NG * TP) + wt0;
    #pragma unroll
    for (int g = 0; g < NG; ++g) {
        const float lo = __shfl(acc[g], 2 * j);
        const float hi = __shfl(acc[g], 2 * j + 1);
        const float v  = (lo + hi) * INV[g];
        if (lane < 32)
            ob[(size_t)g * TP + j] = v;
    }
}

extern "C" void kernel_launch(void* const* d_in, const int* in_sizes, int n_in,
                              void* d_out, int out_size, void* d_ws, size_t ws_size,
                              hipStream_t stream) {
    const float* x    = (const float*)d_in[0];
    const float* W    = (const float*)d_in[1];
    const float* bias = (const float*)d_in[2];
    float* out        = (float*)d_out;

    const int grid = NB * (TP / 128);   // 512 * 8 = 4096 blocks, 4 waves each
    hipLaunchKernelGGL(local_gnn_kernel, dim3(grid), dim3(256), 0, stream,
                       x, W, bias, out);
}